// Round 1
// baseline (1005.814 us; speedup 1.0000x reference)
//
#include <hip/hip_runtime.h>
#include <math.h>

#define NB 8          // batches per block
#define NPART 32      // channel partitions
#define THREADS (NB*NPART)

__device__ __forceinline__ float leaky(float x){ return x >= 0.f ? x : 0.02f*x; }

// Conv over T=9, kernel 3, SAME padding.
// PAD_IN:  input LDS layout [CIN][11][NB], t stored at t+1, pads zeroed.
// !PAD_IN: input LDS layout [CIN][9][NB].
// PAD_OUT: output [COUT][11][NB] padded+zeroed; else [COUT][9][NB] (== flat c*9+t).
template<int CIN, int COUT, int CB, bool PAD_IN, bool PAD_OUT>
__device__ __forceinline__ void conv_layer(
    const float* __restrict__ w, const float* __restrict__ bias,
    const float* __restrict__ in, float* __restrict__ out, int p, int bl)
{
  for (int co = CB*p; co < COUT; co += CB*NPART) {
    float acc[CB][9];
    #pragma unroll
    for (int c=0;c<CB;++c){
      float b = bias[co+c];
      #pragma unroll
      for (int t=0;t<9;++t) acc[c][t] = b;
    }
    for (int ci=0; ci<CIN; ++ci) {
      float a[11];
      if (PAD_IN) {
        const float* base = in + (ci*11)*NB + bl;
        #pragma unroll
        for (int tt=0; tt<11; ++tt) a[tt] = base[tt*NB];
      } else {
        a[0] = 0.f; a[10] = 0.f;
        const float* base = in + (ci*9)*NB + bl;
        #pragma unroll
        for (int tt=0; tt<9; ++tt) a[tt+1] = base[tt*NB];
      }
      #pragma unroll
      for (int c=0;c<CB;++c){
        const float* wp = w + ((size_t)(co+c)*CIN + ci)*3;
        float w0 = wp[0], w1 = wp[1], w2 = wp[2];
        #pragma unroll
        for (int t=0;t<9;++t)
          acc[c][t] = fmaf(w0, a[t], fmaf(w1, a[t+1], fmaf(w2, a[t+2], acc[c][t])));
      }
    }
    #pragma unroll
    for (int c=0;c<CB;++c){
      #pragma unroll
      for (int t=0;t<9;++t){
        float v = leaky(acc[c][t]);
        if (PAD_OUT) out[((co+c)*11 + t+1)*NB + bl] = v;
        else         out[((co+c)*9  + t  )*NB + bl] = v;
      }
      if (PAD_OUT){
        out[((co+c)*11 + 0 )*NB + bl] = 0.f;
        out[((co+c)*11 + 10)*NB + bl] = 0.f;
      }
    }
  }
}

// FC over 9 rows. Input element (row r, feature j) at in[j*SJ + r*SR + bl].
// ACT: 0 = leaky, 1 = tanh. PAD_OUT as above (stride 11, +pads) else stride 9.
template<int NIN, int COUT, int CB, int SJ, int SR, int ACT, bool PAD_OUT>
__device__ __forceinline__ void fc_layer(
    const float* __restrict__ w, const float* __restrict__ bias,
    const float* __restrict__ in, float* __restrict__ out, int p, int bl)
{
  for (int co = CB*p; co < COUT; co += CB*NPART) {
    float acc[CB][9];
    #pragma unroll
    for (int c=0;c<CB;++c){
      float b = bias[co+c];
      #pragma unroll
      for (int r=0;r<9;++r) acc[c][r] = b;
    }
    for (int j=0;j<NIN;++j){
      float a[9];
      const float* base = in + j*SJ + bl;
      #pragma unroll
      for (int r=0;r<9;++r) a[r] = base[r*SR];
      #pragma unroll
      for (int c=0;c<CB;++c){
        float wv = w[(size_t)(co+c)*NIN + j];
        #pragma unroll
        for (int r=0;r<9;++r) acc[c][r] = fmaf(wv, a[r], acc[c][r]);
      }
    }
    #pragma unroll
    for (int c=0;c<CB;++c){
      #pragma unroll
      for (int r=0;r<9;++r){
        float v = acc[c][r];
        v = (ACT==0) ? leaky(v) : tanhf(v);
        if (PAD_OUT) out[((co+c)*11 + r+1)*NB + bl] = v;
        else         out[((co+c)*9  + r  )*NB + bl] = v;
      }
      if (PAD_OUT){
        out[((co+c)*11 + 0 )*NB + bl] = 0.f;
        out[((co+c)*11 + 10)*NB + bl] = 0.f;
      }
    }
  }
}

__global__ __launch_bounds__(THREADS, 2)
void fused_expr_kernel(
    const float* __restrict__ x, const int* __restrict__ ident,
    const float* __restrict__ cw1, const float* __restrict__ cb1,
    const float* __restrict__ cw2, const float* __restrict__ cb2,
    const float* __restrict__ cw3, const float* __restrict__ cb3,
    const float* __restrict__ cw4, const float* __restrict__ cb4,
    const float* __restrict__ fw1, const float* __restrict__ fb1,
    const float* __restrict__ fw2, const float* __restrict__ fb2,
    const float* __restrict__ fw3, const float* __restrict__ fb3,
    const float* __restrict__ aw1, const float* __restrict__ ab1,
    const float* __restrict__ aw2, const float* __restrict__ ab2,
    const float* __restrict__ aw3, const float* __restrict__ ab3,
    const float* __restrict__ aw4, const float* __restrict__ ab4,
    const float* __restrict__ aw5, const float* __restrict__ ab5,
    const float* __restrict__ lw,  const float* __restrict__ lb,
    const float* __restrict__ mapping,
    float* __restrict__ out)
{
  __shared__ float bufA[64*11*NB];    // 22528 B
  __shared__ float bufB[128*9*NB];    // 36864 B
  __shared__ float logits_s[9*NB];
  __shared__ float att_s[9*NB];
  __shared__ float sub_s[32*NB];

  const int tid = threadIdx.x;
  const int p  = tid >> 3;      // partition 0..31
  const int bl = tid & (NB-1);  // local batch 0..7
  const int b0 = blockIdx.x * NB;

  // ---- stage x into bufA [64][11][NB] (padded, h0[c][t] = x[b][t][c]) ----
  for (int i = tid; i < 64*NB; i += THREADS){
    int c = i >> 3, b = i & (NB-1);
    bufA[(c*11 + 0 )*NB + b] = 0.f;
    bufA[(c*11 + 10)*NB + b] = 0.f;
  }
  for (int e = tid; e < NB*576; e += THREADS){
    int b = e / 576, rem = e % 576;
    int t = rem >> 6, c = rem & 63;
    bufA[(c*11 + t+1)*NB + b] = x[(size_t)(b0+b)*576 + rem];
  }
  __syncthreads();

  conv_layer<64, 32, 2, true,  true >(cw1, cb1, bufA, bufB, p, bl); // B:[32][11][NB] (fits: 2816 fl)
  __syncthreads();
  conv_layer<32, 64, 2, true,  true >(cw2, cb2, bufB, bufA, p, bl); // A:[64][11][NB]
  __syncthreads();
  conv_layer<64, 128,4, true,  false>(cw3, cb3, bufA, bufB, p, bl); // B:[128][9][NB]
  __syncthreads();
  conv_layer<128,64, 2, false, false>(cw4, cb4, bufB, bufA, p, bl); // A: flat [576][NB] (c*9+t)
  __syncthreads();
  fc_layer<64, 128, 4, NB,   64*NB, 0, false>(fw1, fb1, bufA, bufB, p, bl); // B:[128][9][NB]
  __syncthreads();
  fc_layer<128, 64, 4, 9*NB, NB,    0, false>(fw2, fb2, bufB, bufA, p, bl); // A:[64][9][NB]
  __syncthreads();
  fc_layer<64,  32, 2, 9*NB, NB,    1, true >(fw3, fb3, bufA, bufB, p, bl); // rs = B:[32][11][NB]
  __syncthreads();

  float* rs = bufB;                       // [32][11][NB] padded, 2816 floats
  float* a1 = bufA;                       // [16][11][NB] 1408
  float* a2 = bufB + 32*11*NB;            // [8][11][NB]  704  (ends 3520 < 9216)
  float* a3 = bufA + 16*11*NB;            // [4][11][NB]  352
  float* a4 = bufB + (32*11 + 8*11)*NB;   // [2][11][NB]  176  (ends 3696)
  float* a5 = bufA + (16*11 + 4*11)*NB;   // [1][11][NB]  88

  conv_layer<32, 16, 2, true, true>(aw1, ab1, rs, a1, p, bl);  __syncthreads();
  conv_layer<16, 8,  2, true, true>(aw2, ab2, a1, a2, p, bl);  __syncthreads();
  conv_layer<8,  4,  2, true, true>(aw3, ab3, a2, a3, p, bl);  __syncthreads();
  conv_layer<4,  2,  2, true, true>(aw4, ab4, a3, a4, p, bl);  __syncthreads();
  conv_layer<2,  1,  1, true, true>(aw5, ab5, a4, a5, p, bl);  __syncthreads();

  // logits[o] = lb[o] + sum_t lw[o][t] * a5[t]
  if (p < 9){
    float acc = lb[p];
    #pragma unroll
    for (int t=0;t<9;++t) acc = fmaf(lw[p*9+t], a5[(t+1)*NB + bl], acc);
    logits_s[p*NB + bl] = acc;
  }
  __syncthreads();

  // softmax over 9 (one thread per batch)
  if (p == 0){
    float m = -1e30f;
    #pragma unroll
    for (int t=0;t<9;++t) m = fmaxf(m, logits_s[t*NB+bl]);
    float s = 0.f; float ex[9];
    #pragma unroll
    for (int t=0;t<9;++t){ ex[t] = __expf(logits_s[t*NB+bl] - m); s += ex[t]; }
    float inv = 1.f/s;
    #pragma unroll
    for (int t=0;t<9;++t) att_s[t*NB+bl] = ex[t]*inv;
  }
  __syncthreads();

  // sub[s] = sum_t rs[s][t] * att[t]   (one thread per (s, batch))
  {
    float acc = 0.f;
    #pragma unroll
    for (int t=0;t<9;++t) acc = fmaf(rs[(p*11 + t+1)*NB + bl], att_s[t*NB+bl], acc);
    sub_s[p*NB + bl] = acc;
  }
  __syncthreads();

  // out[b][e] = 10 * sum_s mapping[id[b]][e][s] * sub[s]
  {
    const int b = b0 + bl;
    const size_t id = (size_t)ident[b];
    const float* mb = mapping + id*53*32;
    float subv[32];
    #pragma unroll
    for (int s=0;s<32;++s) subv[s] = sub_s[s*NB + bl];
    for (int e = p; e < 53; e += NPART){
      const float* mrow = mb + e*32;
      float acc = 0.f;
      #pragma unroll
      for (int s=0;s<32;++s) acc = fmaf(mrow[s], subv[s], acc);
      out[(size_t)b*53 + e] = 10.f*acc;
    }
  }
}

extern "C" void kernel_launch(void* const* d_in, const int* in_sizes, int n_in,
                              void* d_out, int out_size, void* d_ws, size_t ws_size,
                              hipStream_t stream) {
  const float* x    = (const float*)d_in[0];
  const int*   ident= (const int*)  d_in[1];
  const float* cw1  = (const float*)d_in[2];  const float* cb1 = (const float*)d_in[3];
  const float* cw2  = (const float*)d_in[4];  const float* cb2 = (const float*)d_in[5];
  const float* cw3  = (const float*)d_in[6];  const float* cb3 = (const float*)d_in[7];
  const float* cw4  = (const float*)d_in[8];  const float* cb4 = (const float*)d_in[9];
  const float* fw1  = (const float*)d_in[10]; const float* fb1 = (const float*)d_in[11];
  const float* fw2  = (const float*)d_in[12]; const float* fb2 = (const float*)d_in[13];
  const float* fw3  = (const float*)d_in[14]; const float* fb3 = (const float*)d_in[15];
  const float* aw1  = (const float*)d_in[16]; const float* ab1 = (const float*)d_in[17];
  const float* aw2  = (const float*)d_in[18]; const float* ab2 = (const float*)d_in[19];
  const float* aw3  = (const float*)d_in[20]; const float* ab3 = (const float*)d_in[21];
  const float* aw4  = (const float*)d_in[22]; const float* ab4 = (const float*)d_in[23];
  const float* aw5  = (const float*)d_in[24]; const float* ab5 = (const float*)d_in[25];
  const float* lw   = (const float*)d_in[26]; const float* lb  = (const float*)d_in[27];
  const float* mapping = (const float*)d_in[28];

  const int B = 32768;
  dim3 grid(B / NB), block(THREADS);
  fused_expr_kernel<<<grid, block, 0, stream>>>(
      x, ident, cw1, cb1, cw2, cb2, cw3, cb3, cw4, cb4,
      fw1, fb1, fw2, fb2, fw3, fb3,
      aw1, ab1, aw2, ab2, aw3, ab3, aw4, ab4, aw5, ab5,
      lw, lb, mapping, (float*)d_out);
}

// Round 2
// 229.741 us; speedup vs baseline: 4.3780x; 4.3780x over previous
//
#include <hip/hip_runtime.h>
#include <math.h>

#define THREADS 256
#define NB 16            // batches per block  -> M = 144 rows, 9 M-tiles

typedef __attribute__((ext_vector_type(8))) short bf16x8;
typedef __attribute__((ext_vector_type(4))) float f32x4;

__device__ __forceinline__ float leaky(float x){ return x >= 0.f ? x : 0.02f*x; }

__device__ __forceinline__ unsigned short f2bf(float f){
  union { float f; unsigned u; } v; v.f = f;
  unsigned r = (v.u + 0x7FFFu + ((v.u >> 16) & 1u)) >> 16;
  return (unsigned short)r;
}
__device__ __forceinline__ float bf2f(unsigned short h){
  union { unsigned u; float f; } v; v.u = ((unsigned)h) << 16;
  return v.f;
}

template<int L2R>
__device__ __forceinline__ unsigned swz(unsigned b){
  if constexpr (L2R < 0) return b;
  else return b ^ (((b >> L2R) & 7u) << 4);
}

__device__ __forceinline__ f32x4 mfma16(bf16x8 a, bf16x8 b, f32x4 c){
  return __builtin_amdgcn_mfma_f32_16x16x32_bf16(a, b, c, 0, 0, 0);
}

// ---------------- MFMA conv layer (k=3, SAME pad, T=9) ----------------
// in : bf16 LDS, padded layout [bl][11][CIN], row t stored at t+1, pads zero
// out: OUT_MODE 0 -> padded [bl][11][COUT]; OUT_MODE 2 -> conv4-flat [bl][576] (c*9+t)
template<int CIN, int COUT, int L2RI, int L2RO, int OUT_MODE>
__device__ __forceinline__ void mfma_conv(const float* __restrict__ w,
    const float* __restrict__ bias, const char* __restrict__ inb,
    char* __restrict__ outb, int tid)
{
  constexpr int KS = (CIN*3)/32;
  constexpr int NT = COUT/16;
  constexpr int L2CIN = (CIN==16?4:CIN==32?5:CIN==64?6:7);
  constexpr int MYNT = (NT >= 4) ? NT/4 : 1;
  const int wave = tid >> 6, lane = tid & 63;
  const int hi = lane >> 4, lo = lane & 15;

  int nt0, mlo, mhi;
  if constexpr (NT >= 4) { nt0 = wave*MYNT; mlo = 0; mhi = 9; }
  else { constexpr int WPN = 4/NT; nt0 = wave % NT; int seg = wave / NT;
         mlo = (9*seg)/WPN; mhi = (9*(seg+1))/WPN; }

  // B fragments: B[k = dt*CIN+ci][n] = w[n][ci][dt]
  bf16x8 Bf[MYNT][KS];
  #pragma unroll
  for (int nt = 0; nt < MYNT; ++nt){
    int n = (nt0+nt)*16 + lo;
    #pragma unroll
    for (int ks = 0; ks < KS; ++ks){
      int k0 = ks*32 + hi*8;
      int dt = k0 >> L2CIN, ci0 = k0 & (CIN-1);
      const float* wp = w + ((size_t)n*CIN + ci0)*3 + dt;
      #pragma unroll
      for (int j = 0; j < 8; ++j) Bf[nt][ks][j] = (short)f2bf(wp[j*3]);
    }
  }

  for (int m = mlo; m < mhi; ++m){
    int R = m*16 + lo;
    int bl = R/9, t = R - bl*9;
    int ridx = bl*11 + t;                 // +dt gives tap row (pad at 0 and 10)
    bf16x8 Af[KS];
    #pragma unroll
    for (int ks = 0; ks < KS; ++ks){
      int k0 = ks*32 + hi*8;
      int dt = k0 >> L2CIN, ci0 = k0 & (CIN-1);
      unsigned byte = (unsigned)(((ridx + dt)*CIN + ci0)*2);
      Af[ks] = *(const bf16x8*)(inb + swz<L2RI>(byte));
    }
    f32x4 acc[MYNT];
    #pragma unroll
    for (int nt = 0; nt < MYNT; ++nt){
      float bv = bias[(nt0+nt)*16 + lo];
      acc[nt] = (f32x4){bv, bv, bv, bv};
      #pragma unroll
      for (int ks = 0; ks < KS; ++ks)
        acc[nt] = mfma16(Af[ks], Bf[nt][ks], acc[nt]);
    }
    #pragma unroll
    for (int nt = 0; nt < MYNT; ++nt){
      int n = (nt0+nt)*16 + lo;
      #pragma unroll
      for (int r = 0; r < 4; ++r){
        int R2 = m*16 + hi*4 + r;
        int bl2 = R2/9, t2 = R2 - bl2*9;
        float v = leaky(acc[nt][r]);
        unsigned byte;
        if constexpr (OUT_MODE == 0) byte = (unsigned)(((bl2*11 + t2 + 1)*COUT + n)*2);
        else                         byte = (unsigned)((bl2*576 + n*9 + t2)*2);
        *(short*)(outb + swz<L2RO>(byte)) = (short)f2bf(v);
      }
    }
  }
  if constexpr (OUT_MODE == 0){
    for (int i = tid; i < NB*2*COUT; i += THREADS){
      int bl = i / (2*COUT); int rem = i - bl*2*COUT;
      int side = rem / COUT; int c = rem - side*COUT;
      unsigned byte = (unsigned)(((bl*11 + side*10)*COUT + c)*2);
      *(short*)(outb + swz<L2RO>(byte)) = 0;
    }
  }
}

// ---------------- MFMA FC layer ----------------
// in : bf16 LDS flat rows: elem (R, j) at (R*K + j)*2
// out: OUT_MODE 1 flat (R*COUT+n); OUT_MODE 0 padded [bl][11][COUT]
template<int K, int COUT, int L2RI, int L2RO, int ACT, int OUT_MODE>
__device__ __forceinline__ void mfma_fc(const float* __restrict__ w,
    const float* __restrict__ bias, const char* __restrict__ inb,
    char* __restrict__ outb, int tid)
{
  constexpr int KS = K/32;
  constexpr int NT = COUT/16;
  constexpr int MYNT = (NT >= 4) ? NT/4 : 1;
  const int wave = tid >> 6, lane = tid & 63;
  const int hi = lane >> 4, lo = lane & 15;

  int nt0, mlo, mhi;
  if constexpr (NT >= 4) { nt0 = wave*MYNT; mlo = 0; mhi = 9; }
  else { constexpr int WPN = 4/NT; nt0 = wave % NT; int seg = wave / NT;
         mlo = (9*seg)/WPN; mhi = (9*(seg+1))/WPN; }

  bf16x8 Bf[MYNT][KS];
  #pragma unroll
  for (int nt = 0; nt < MYNT; ++nt){
    int n = (nt0+nt)*16 + lo;
    #pragma unroll
    for (int ks = 0; ks < KS; ++ks){
      int k0 = ks*32 + hi*8;
      const float* wp = w + (size_t)n*K + k0;
      #pragma unroll
      for (int j = 0; j < 8; ++j) Bf[nt][ks][j] = (short)f2bf(wp[j]);
    }
  }

  for (int m = mlo; m < mhi; ++m){
    int R = m*16 + lo;
    bf16x8 Af[KS];
    #pragma unroll
    for (int ks = 0; ks < KS; ++ks){
      unsigned byte = (unsigned)((R*K + ks*32 + hi*8)*2);
      Af[ks] = *(const bf16x8*)(inb + swz<L2RI>(byte));
    }
    f32x4 acc[MYNT];
    #pragma unroll
    for (int nt = 0; nt < MYNT; ++nt){
      float bv = bias[(nt0+nt)*16 + lo];
      acc[nt] = (f32x4){bv, bv, bv, bv};
      #pragma unroll
      for (int ks = 0; ks < KS; ++ks)
        acc[nt] = mfma16(Af[ks], Bf[nt][ks], acc[nt]);
    }
    #pragma unroll
    for (int nt = 0; nt < MYNT; ++nt){
      int n = (nt0+nt)*16 + lo;
      #pragma unroll
      for (int r = 0; r < 4; ++r){
        int R2 = m*16 + hi*4 + r;
        float v = acc[nt][r];
        v = (ACT == 0) ? leaky(v) : tanhf(v);
        unsigned byte;
        if constexpr (OUT_MODE == 1) byte = (unsigned)((R2*COUT + n)*2);
        else { int bl2 = R2/9, t2 = R2 - bl2*9;
               byte = (unsigned)(((bl2*11 + t2 + 1)*COUT + n)*2); }
        *(short*)(outb + swz<L2RO>(byte)) = (short)f2bf(v);
      }
    }
  }
  if constexpr (OUT_MODE == 0){
    for (int i = tid; i < NB*2*COUT; i += THREADS){
      int bl = i / (2*COUT); int rem = i - bl*2*COUT;
      int side = rem / COUT; int c = rem - side*COUT;
      unsigned byte = (unsigned)(((bl*11 + side*10)*COUT + c)*2);
      *(short*)(outb + swz<L2RO>(byte)) = 0;
    }
  }
}

// ---------------- small VALU conv (attention tail) ----------------
template<int CIN, int COUT, int L2RI, int L2RO>
__device__ __forceinline__ void valu_conv(const float* __restrict__ w,
    const float* __restrict__ bias, const char* __restrict__ inb,
    char* __restrict__ outb, int tid)
{
  int p = tid >> 4, bl = tid & 15;
  if (p < COUT){
    float acc[9];
    float bv = bias[p];
    #pragma unroll
    for (int t = 0; t < 9; ++t) acc[t] = bv;
    for (int ci = 0; ci < CIN; ++ci){
      float a[11];
      #pragma unroll
      for (int tt = 0; tt < 11; ++tt){
        unsigned byte = (unsigned)(((bl*11 + tt)*CIN + ci)*2);
        a[tt] = bf2f(*(const unsigned short*)(inb + swz<L2RI>(byte)));
      }
      const float* wp = w + ((size_t)p*CIN + ci)*3;
      float w0 = wp[0], w1 = wp[1], w2 = wp[2];
      #pragma unroll
      for (int t = 0; t < 9; ++t)
        acc[t] = fmaf(w0, a[t], fmaf(w1, a[t+1], fmaf(w2, a[t+2], acc[t])));
    }
    #pragma unroll
    for (int t = 0; t < 9; ++t){
      unsigned byte = (unsigned)(((bl*11 + t + 1)*COUT + p)*2);
      *(short*)(outb + swz<L2RO>(byte)) = (short)f2bf(leaky(acc[t]));
    }
    *(short*)(outb + swz<L2RO>((unsigned)(((bl*11 + 0 )*COUT + p)*2))) = 0;
    *(short*)(outb + swz<L2RO>((unsigned)(((bl*11 + 10)*COUT + p)*2))) = 0;
  }
}

__global__ __launch_bounds__(THREADS, 2)
void fused_expr_kernel(
    const float* __restrict__ x, const int* __restrict__ ident,
    const float* __restrict__ cw1, const float* __restrict__ cb1,
    const float* __restrict__ cw2, const float* __restrict__ cb2,
    const float* __restrict__ cw3, const float* __restrict__ cb3,
    const float* __restrict__ cw4, const float* __restrict__ cb4,
    const float* __restrict__ fw1, const float* __restrict__ fb1,
    const float* __restrict__ fw2, const float* __restrict__ fb2,
    const float* __restrict__ fw3, const float* __restrict__ fb3,
    const float* __restrict__ aw1, const float* __restrict__ ab1,
    const float* __restrict__ aw2, const float* __restrict__ ab2,
    const float* __restrict__ aw3, const float* __restrict__ ab3,
    const float* __restrict__ aw4, const float* __restrict__ ab4,
    const float* __restrict__ aw5, const float* __restrict__ ab5,
    const float* __restrict__ lw,  const float* __restrict__ lb,
    const float* __restrict__ mapping,
    float* __restrict__ out)
{
  __shared__ __align__(16) char pool[67584];
  __shared__ float logits_s[NB*9];
  __shared__ float att_s[NB*9];
  __shared__ float sub_s[NB*32];

  char* RA = pool;            // 45056 bytes
  char* RB = pool + 45056;    // 22528 bytes

  const int tid = threadIdx.x;
  const int b0 = blockIdx.x * NB;
  const int p  = tid >> 4;
  const int bl = tid & 15;

  // ---- stage x (fp32 global, (B,9,64)) -> RB bf16 [bl][11][64] padded, swz<7>
  {
    const float* xb = x + (size_t)b0 * 576;
    for (int i = tid; i < NB*576; i += THREADS){
      int b = i / 576; int f = i - b*576;      // f = t*64 + c
      int t = f >> 6;  int c = f & 63;
      unsigned byte = (unsigned)(((b*11 + t + 1)*64 + c)*2);
      *(short*)(RB + swz<7>(byte)) = (short)f2bf(xb[i]);
    }
    for (int i = tid; i < NB*2*64; i += THREADS){
      int b = i >> 7; int rem = i & 127;
      int side = rem >> 6; int c = rem & 63;
      unsigned byte = (unsigned)(((b*11 + side*10)*64 + c)*2);
      *(short*)(RB + swz<7>(byte)) = 0;
    }
  }
  __syncthreads();

  mfma_conv<64, 32, 7, 6, 0>(cw1, cb1, RB, RA, tid);  __syncthreads();
  mfma_conv<32, 64, 6, 7, 0>(cw2, cb2, RA, RB, tid);  __syncthreads();
  mfma_conv<64, 128, 7, 8, 0>(cw3, cb3, RB, RA, tid); __syncthreads();
  mfma_conv<128, 64, 8, 7, 2>(cw4, cb4, RA, RB, tid); __syncthreads();   // flat [bl][576]
  mfma_fc<64, 128, 7, 8, 0, 1>(fw1, fb1, RB, RA, tid); __syncthreads();  // flat [R][128]
  mfma_fc<128, 64, 8, 7, 0, 1>(fw2, fb2, RA, RB, tid); __syncthreads(); // flat [R][64]
  mfma_fc<64, 32, 7, 6, 1, 0>(fw3, fb3, RB, RA, tid);  __syncthreads(); // rs padded [bl][11][32]

  char* rs = RA;                 // 11264 B, live until the end
  char* a1 = RB;                 // [bl][11][16] 5632 B
  char* a2 = RA + 11264;         // [bl][11][8]  2816 B
  char* a3 = RB + 5632;          // [bl][11][4]  1408 B
  char* a4 = RA + 14080;         // [bl][11][2]   704 B
  char* a5 = RB + 7040;          // [bl][11][1]   352 B

  mfma_conv<32, 16, 6, 5, 0>(aw1, ab1, rs, a1, tid);  __syncthreads();
  valu_conv<16, 8, 5, -1>(aw2, ab2, a1, a2, tid);     __syncthreads();
  valu_conv<8, 4, -1, -1>(aw3, ab3, a2, a3, tid);     __syncthreads();
  valu_conv<4, 2, -1, -1>(aw4, ab4, a3, a4, tid);     __syncthreads();
  valu_conv<2, 1, -1, -1>(aw5, ab5, a4, a5, tid);     __syncthreads();

  // logits[b][o] = lb[o] + sum_t a5[b][t] * lw[o][t]
  if (p < 9){
    float acc = lb[p];
    #pragma unroll
    for (int t = 0; t < 9; ++t)
      acc = fmaf(lw[p*9 + t], bf2f(*(const unsigned short*)(a5 + (bl*11 + t + 1)*2)), acc);
    logits_s[bl*9 + p] = acc;
  }
  __syncthreads();

  if (p == 0){
    float m = -1e30f;
    #pragma unroll
    for (int t = 0; t < 9; ++t) m = fmaxf(m, logits_s[bl*9 + t]);
    float s = 0.f, ex[9];
    #pragma unroll
    for (int t = 0; t < 9; ++t){ ex[t] = __expf(logits_s[bl*9 + t] - m); s += ex[t]; }
    float inv = 1.f / s;
    #pragma unroll
    for (int t = 0; t < 9; ++t) att_s[bl*9 + t] = ex[t]*inv;
  }
  __syncthreads();

  // sub[b][s] = sum_t rs[b][s][t] * att[b][t]   (rs: [bl][11][32] swz<6>)
  #pragma unroll
  for (int sh = 0; sh < 2; ++sh){
    int s = p + sh*16;
    float acc = 0.f;
    #pragma unroll
    for (int t = 0; t < 9; ++t){
      unsigned byte = (unsigned)(((bl*11 + t + 1)*32 + s)*2);
      acc = fmaf(bf2f(*(const unsigned short*)(rs + swz<6>(byte))), att_s[bl*9 + t], acc);
    }
    sub_s[bl*32 + s] = acc;
  }
  __syncthreads();

  // out[b][e] = 10 * sum_s mapping[id[b]][e][s] * sub[b][s]
  {
    const int b = b0 + bl;
    const size_t id = (size_t)ident[b];
    const float* mb = mapping + id*53*32;
    float subv[32];
    #pragma unroll
    for (int s = 0; s < 32; ++s) subv[s] = sub_s[bl*32 + s];
    for (int e = p; e < 53; e += 16){
      const float* mrow = mb + e*32;
      float acc = 0.f;
      #pragma unroll
      for (int s = 0; s < 32; ++s) acc = fmaf(mrow[s], subv[s], acc);
      out[(size_t)b*53 + e] = 10.f*acc;
    }
  }
}

extern "C" void kernel_launch(void* const* d_in, const int* in_sizes, int n_in,
                              void* d_out, int out_size, void* d_ws, size_t ws_size,
                              hipStream_t stream) {
  const float* x    = (const float*)d_in[0];
  const int*   ident= (const int*)  d_in[1];
  const float* cw1  = (const float*)d_in[2];  const float* cb1 = (const float*)d_in[3];
  const float* cw2  = (const float*)d_in[4];  const float* cb2 = (const float*)d_in[5];
  const float* cw3  = (const float*)d_in[6];  const float* cb3 = (const float*)d_in[7];
  const float* cw4  = (const float*)d_in[8];  const float* cb4 = (const float*)d_in[9];
  const float* fw1  = (const float*)d_in[10]; const float* fb1 = (const float*)d_in[11];
  const float* fw2  = (const float*)d_in[12]; const float* fb2 = (const float*)d_in[13];
  const float* fw3  = (const float*)d_in[14]; const float* fb3 = (const float*)d_in[15];
  const float* aw1  = (const float*)d_in[16]; const float* ab1 = (const float*)d_in[17];
  const float* aw2  = (const float*)d_in[18]; const float* ab2 = (const float*)d_in[19];
  const float* aw3  = (const float*)d_in[20]; const float* ab3 = (const float*)d_in[21];
  const float* aw4  = (const float*)d_in[22]; const float* ab4 = (const float*)d_in[23];
  const float* aw5  = (const float*)d_in[24]; const float* ab5 = (const float*)d_in[25];
  const float* lw   = (const float*)d_in[26]; const float* lb  = (const float*)d_in[27];
  const float* mapping = (const float*)d_in[28];

  const int B = 32768;
  dim3 grid(B / NB), block(THREADS);
  fused_expr_kernel<<<grid, block, 0, stream>>>(
      x, ident, cw1, cb1, cw2, cb2, cw3, cb3, cw4, cb4,
      fw1, fb1, fw2, fb2, fw3, fb3,
      aw1, ab1, aw2, ab2, aw3, ab3, aw4, ab4, aw5, ab5,
      lw, lb, mapping, (float*)d_out);
}

// Round 3
// 166.189 us; speedup vs baseline: 6.0522x; 1.3824x over previous
//
#include <hip/hip_runtime.h>
#include <math.h>

#define THREADS 512
#define WAVES (THREADS/64)
#define NB 16            // batches per block -> M = 144 rows, 9 M-tiles

typedef __attribute__((ext_vector_type(8))) short bf16x8;
typedef __attribute__((ext_vector_type(4))) float f32x4;

__device__ __forceinline__ float leaky(float x){ return x >= 0.f ? x : 0.02f*x; }
__device__ __forceinline__ float fast_tanh(float x){
  float e = __expf(2.f*x);
  return 1.f - 2.f/(e + 1.f);
}

__device__ __forceinline__ unsigned short f2bf(float f){
  union { float f; unsigned u; } v; v.f = f;
  unsigned r = (v.u + 0x7FFFu + ((v.u >> 16) & 1u)) >> 16;
  return (unsigned short)r;
}
__device__ __forceinline__ float bf2f(unsigned short h){
  union { unsigned u; float f; } v; v.u = ((unsigned)h) << 16;
  return v.f;
}

template<int L2R>
__device__ __forceinline__ unsigned swz(unsigned b){
  if constexpr (L2R < 0) return b;
  else return b ^ (((b >> L2R) & 7u) << 4);
}

__device__ __forceinline__ f32x4 mfma16(bf16x8 a, bf16x8 b, f32x4 c){
  return __builtin_amdgcn_mfma_f32_16x16x32_bf16(a, b, c, 0, 0, 0);
}

// ---- packed weight layout offsets (bf16 elements) ----
#define WB_C1 0
#define WB_C2 6144
#define WB_C3 12288
#define WB_C4 36864
#define WB_F1 61440
#define WB_F2 69632
#define WB_F3 77824
#define WB_A1 79872
#define WP_TOTAL 81408   // elements; *2 bytes = 162816 B

__global__ void pack_weights(
    const float* __restrict__ cw1, const float* __restrict__ cw2,
    const float* __restrict__ cw3, const float* __restrict__ cw4,
    const float* __restrict__ fw1, const float* __restrict__ fw2,
    const float* __restrict__ fw3, const float* __restrict__ aw1,
    short* __restrict__ wp)
{
  int g = blockIdx.x*256 + threadIdx.x;
  if (g >= WP_TOTAL) return;
  const float* w; int base, l2c, KS, conv;
  if      (g < WB_C2){ w=cw1; base=WB_C1; l2c=6; KS=6;  conv=1; }
  else if (g < WB_C3){ w=cw2; base=WB_C2; l2c=5; KS=3;  conv=1; }
  else if (g < WB_C4){ w=cw3; base=WB_C3; l2c=6; KS=6;  conv=1; }
  else if (g < WB_F1){ w=cw4; base=WB_C4; l2c=7; KS=12; conv=1; }
  else if (g < WB_F2){ w=fw1; base=WB_F1; l2c=6; KS=2;  conv=0; }
  else if (g < WB_F3){ w=fw2; base=WB_F2; l2c=7; KS=4;  conv=0; }
  else if (g < WB_A1){ w=fw3; base=WB_F3; l2c=6; KS=2;  conv=0; }
  else               { w=aw1; base=WB_A1; l2c=5; KS=3;  conv=1; }
  int local = g - base;
  int frag = local >> 9;          // 512 elements per fragment
  int lane = (local >> 3) & 63;
  int j    = local & 7;
  int nt = frag / KS, ks = frag - nt*KS;
  int hi = lane >> 4, lo = lane & 15;
  int k = ks*32 + hi*8 + j;       // B row (K index)
  int n = nt*16 + lo;             // B col (out channel)
  float v;
  if (conv){
    int dt = k >> l2c, ci = k & ((1<<l2c)-1);
    v = w[(((size_t)n << l2c) + ci)*3 + dt];
  } else {
    v = w[((size_t)n << l2c) + k];
  }
  wp[g] = (short)f2bf(v);
}

// ---------------- MFMA conv layer (k=3, SAME pad, T=9) ----------------
// in : bf16 LDS, padded layout [bl][11][CIN], row t stored at t+1, pads zero
// out: OUT_MODE 0 -> padded [bl][11][COUT]; OUT_MODE 2 -> conv4-flat [bl][576] (c*9+t)
template<int CIN, int COUT, int L2RI, int L2RO, int OUT_MODE, int LBASE, bool PACKED>
__device__ __forceinline__ void mfma_conv(
    const short* __restrict__ wp, const float* __restrict__ w,
    const float* __restrict__ bias, const char* __restrict__ inb,
    char* __restrict__ outb, int tid)
{
  constexpr int KS = (CIN*3)/32;
  constexpr int NT = COUT/16;
  constexpr int L2CIN = (CIN==16?4:CIN==32?5:CIN==64?6:7);
  constexpr int MYNT = (NT >= WAVES) ? NT/WAVES : 1;
  const int wave = tid >> 6, lane = tid & 63;
  const int hi = lane >> 4, lo = lane & 15;

  int nt0, mlo, mhi;
  if constexpr (NT >= WAVES) { nt0 = wave*MYNT; mlo = 0; mhi = 9; }
  else { constexpr int WPN = WAVES/NT; int seg = wave / NT; nt0 = wave - seg*NT;
         mlo = (9*seg)/WPN; mhi = (9*(seg+1))/WPN; }

  bf16x8 Bf[MYNT][KS];
  #pragma unroll
  for (int nt = 0; nt < MYNT; ++nt){
    #pragma unroll
    for (int ks = 0; ks < KS; ++ks){
      if constexpr (PACKED){
        Bf[nt][ks] = *(const bf16x8*)(wp + LBASE + (((nt0+nt)*KS + ks)<<9) + lane*8);
      } else {
        int n = (nt0+nt)*16 + lo;
        int k0 = ks*32 + hi*8;
        int dt = k0 >> L2CIN, ci0 = k0 & (CIN-1);
        const float* wq = w + ((size_t)n*CIN + ci0)*3 + dt;
        #pragma unroll
        for (int j = 0; j < 8; ++j) Bf[nt][ks][j] = (short)f2bf(wq[j*3]);
      }
    }
  }

  for (int m = mlo; m < mhi; ++m){
    int R = m*16 + lo;
    int bl = R/9, t = R - bl*9;
    int ridx = bl*11 + t;                 // +dt gives tap row (pads at 0 and 10)
    f32x4 acc[MYNT];
    #pragma unroll
    for (int nt = 0; nt < MYNT; ++nt){
      float bv = bias[(nt0+nt)*16 + lo];
      acc[nt] = (f32x4){bv, bv, bv, bv};
    }
    #pragma unroll
    for (int ks = 0; ks < KS; ++ks){
      int k0 = ks*32 + hi*8;
      int dt = k0 >> L2CIN, ci0 = k0 & (CIN-1);
      unsigned byte = (unsigned)(((ridx + dt)*CIN + ci0)*2);
      bf16x8 Af = *(const bf16x8*)(inb + swz<L2RI>(byte));
      #pragma unroll
      for (int nt = 0; nt < MYNT; ++nt)
        acc[nt] = mfma16(Af, Bf[nt][ks], acc[nt]);
    }
    #pragma unroll
    for (int nt = 0; nt < MYNT; ++nt){
      int n = (nt0+nt)*16 + lo;
      #pragma unroll
      for (int r = 0; r < 4; ++r){
        int R2 = m*16 + hi*4 + r;
        int bl2 = R2/9, t2 = R2 - bl2*9;
        float v = leaky(acc[nt][r]);
        unsigned byte;
        if constexpr (OUT_MODE == 0) byte = (unsigned)(((bl2*11 + t2 + 1)*COUT + n)*2);
        else                         byte = (unsigned)((bl2*576 + n*9 + t2)*2);
        *(short*)(outb + swz<L2RO>(byte)) = (short)f2bf(v);
      }
    }
  }
  if constexpr (OUT_MODE == 0){
    for (int i = tid; i < NB*2*COUT; i += THREADS){
      int bl = i / (2*COUT); int rem = i - bl*2*COUT;
      int side = rem / COUT; int c = rem - side*COUT;
      unsigned byte = (unsigned)(((bl*11 + side*10)*COUT + c)*2);
      *(short*)(outb + swz<L2RO>(byte)) = 0;
    }
  }
}

// ---------------- MFMA FC layer ----------------
// in : bf16 LDS flat rows: elem (R, j) at (R*K + j)*2
// out: OUT_MODE 1 flat (R*COUT+n); OUT_MODE 0 padded [bl][11][COUT]
template<int K, int COUT, int L2RI, int L2RO, int ACT, int OUT_MODE, int LBASE, bool PACKED>
__device__ __forceinline__ void mfma_fc(
    const short* __restrict__ wp, const float* __restrict__ w,
    const float* __restrict__ bias, const char* __restrict__ inb,
    char* __restrict__ outb, int tid)
{
  constexpr int KS = K/32;
  constexpr int NT = COUT/16;
  constexpr int MYNT = (NT >= WAVES) ? NT/WAVES : 1;
  const int wave = tid >> 6, lane = tid & 63;
  const int hi = lane >> 4, lo = lane & 15;

  int nt0, mlo, mhi;
  if constexpr (NT >= WAVES) { nt0 = wave*MYNT; mlo = 0; mhi = 9; }
  else { constexpr int WPN = WAVES/NT; int seg = wave / NT; nt0 = wave - seg*NT;
         mlo = (9*seg)/WPN; mhi = (9*(seg+1))/WPN; }

  bf16x8 Bf[MYNT][KS];
  #pragma unroll
  for (int nt = 0; nt < MYNT; ++nt){
    #pragma unroll
    for (int ks = 0; ks < KS; ++ks){
      if constexpr (PACKED){
        Bf[nt][ks] = *(const bf16x8*)(wp + LBASE + (((nt0+nt)*KS + ks)<<9) + lane*8);
      } else {
        int n = (nt0+nt)*16 + lo;
        int k0 = ks*32 + hi*8;
        const float* wq = w + (size_t)n*K + k0;
        #pragma unroll
        for (int j = 0; j < 8; ++j) Bf[nt][ks][j] = (short)f2bf(wq[j]);
      }
    }
  }

  for (int m = mlo; m < mhi; ++m){
    int R = m*16 + lo;
    f32x4 acc[MYNT];
    #pragma unroll
    for (int nt = 0; nt < MYNT; ++nt){
      float bv = bias[(nt0+nt)*16 + lo];
      acc[nt] = (f32x4){bv, bv, bv, bv};
    }
    #pragma unroll
    for (int ks = 0; ks < KS; ++ks){
      unsigned byte = (unsigned)((R*K + ks*32 + hi*8)*2);
      bf16x8 Af = *(const bf16x8*)(inb + swz<L2RI>(byte));
      #pragma unroll
      for (int nt = 0; nt < MYNT; ++nt)
        acc[nt] = mfma16(Af, Bf[nt][ks], acc[nt]);
    }
    #pragma unroll
    for (int nt = 0; nt < MYNT; ++nt){
      int n = (nt0+nt)*16 + lo;
      #pragma unroll
      for (int r = 0; r < 4; ++r){
        int R2 = m*16 + hi*4 + r;
        float v = acc[nt][r];
        v = (ACT == 0) ? leaky(v) : fast_tanh(v);
        unsigned byte;
        if constexpr (OUT_MODE == 1) byte = (unsigned)((R2*COUT + n)*2);
        else { int bl2 = R2/9, t2 = R2 - bl2*9;
               byte = (unsigned)(((bl2*11 + t2 + 1)*COUT + n)*2); }
        *(short*)(outb + swz<L2RO>(byte)) = (short)f2bf(v);
      }
    }
  }
  if constexpr (OUT_MODE == 0){
    for (int i = tid; i < NB*2*COUT; i += THREADS){
      int bl = i / (2*COUT); int rem = i - bl*2*COUT;
      int side = rem / COUT; int c = rem - side*COUT;
      unsigned byte = (unsigned)(((bl*11 + side*10)*COUT + c)*2);
      *(short*)(outb + swz<L2RO>(byte)) = 0;
    }
  }
}

// ---------------- small VALU conv (attention tail) ----------------
template<int CIN, int COUT, int L2RI, int L2RO>
__device__ __forceinline__ void valu_conv(const float* __restrict__ w,
    const float* __restrict__ bias, const char* __restrict__ inb,
    char* __restrict__ outb, int tid)
{
  int p = tid >> 4, bl = tid & 15;
  if (p < COUT){
    float acc[9];
    float bv = bias[p];
    #pragma unroll
    for (int t = 0; t < 9; ++t) acc[t] = bv;
    for (int ci = 0; ci < CIN; ++ci){
      float a[11];
      #pragma unroll
      for (int tt = 0; tt < 11; ++tt){
        unsigned byte = (unsigned)(((bl*11 + tt)*CIN + ci)*2);
        a[tt] = bf2f(*(const unsigned short*)(inb + swz<L2RI>(byte)));
      }
      const float* wq = w + ((size_t)p*CIN + ci)*3;
      float w0 = wq[0], w1 = wq[1], w2 = wq[2];
      #pragma unroll
      for (int t = 0; t < 9; ++t)
        acc[t] = fmaf(w0, a[t], fmaf(w1, a[t+1], fmaf(w2, a[t+2], acc[t])));
    }
    #pragma unroll
    for (int t = 0; t < 9; ++t){
      unsigned byte = (unsigned)(((bl*11 + t + 1)*COUT + p)*2);
      *(short*)(outb + swz<L2RO>(byte)) = (short)f2bf(leaky(acc[t]));
    }
    *(short*)(outb + swz<L2RO>((unsigned)(((bl*11 + 0 )*COUT + p)*2))) = 0;
    *(short*)(outb + swz<L2RO>((unsigned)(((bl*11 + 10)*COUT + p)*2))) = 0;
  }
}

template<bool PACKED>
__global__ __launch_bounds__(THREADS, 4)
void fused_expr_kernel(
    const float* __restrict__ x, const int* __restrict__ ident,
    const float* __restrict__ cw1, const float* __restrict__ cb1,
    const float* __restrict__ cw2, const float* __restrict__ cb2,
    const float* __restrict__ cw3, const float* __restrict__ cb3,
    const float* __restrict__ cw4, const float* __restrict__ cb4,
    const float* __restrict__ fw1, const float* __restrict__ fb1,
    const float* __restrict__ fw2, const float* __restrict__ fb2,
    const float* __restrict__ fw3, const float* __restrict__ fb3,
    const float* __restrict__ aw1, const float* __restrict__ ab1,
    const float* __restrict__ aw2, const float* __restrict__ ab2,
    const float* __restrict__ aw3, const float* __restrict__ ab3,
    const float* __restrict__ aw4, const float* __restrict__ ab4,
    const float* __restrict__ aw5, const float* __restrict__ ab5,
    const float* __restrict__ lw,  const float* __restrict__ lb,
    const float* __restrict__ mapping, const short* __restrict__ wp,
    float* __restrict__ out)
{
  __shared__ __align__(16) char pool[67584];
  __shared__ float logits_s[NB*9];
  __shared__ float att_s[NB*9];
  __shared__ float sub_s[NB*32];

  char* RA = pool;            // 45056 bytes
  char* RB = pool + 45056;    // 22528 bytes

  const int tid = threadIdx.x;
  const int b0 = blockIdx.x * NB;
  const int p  = tid >> 4;    // 0..31
  const int bl = tid & 15;

  // ---- stage x (fp32 global, (B,9,64)) -> RB bf16 [bl][11][64] padded, swz<7>
  {
    const float4* xb4 = (const float4*)(x + (size_t)b0 * 576);
    for (int i = tid; i < NB*144; i += THREADS){
      int b = i / 144; int rem = i - b*144;     // rem = t*16 + c4
      int t = rem >> 4; int c4 = rem & 15;
      float4 v = xb4[i];
      uint2 pk;
      pk.x = (unsigned)f2bf(v.x) | ((unsigned)f2bf(v.y) << 16);
      pk.y = (unsigned)f2bf(v.z) | ((unsigned)f2bf(v.w) << 16);
      unsigned byte = (unsigned)(((b*11 + t + 1)*64 + c4*4)*2);
      *(uint2*)(RB + swz<7>(byte)) = pk;
    }
    for (int i = tid; i < 512; i += THREADS){
      int b = i >> 5; int rem = i & 31;
      int side = rem >> 4; int c4 = rem & 15;
      unsigned byte = (unsigned)(((b*11 + side*10)*64 + c4*4)*2);
      uint2 z; z.x = 0u; z.y = 0u;
      *(uint2*)(RB + swz<7>(byte)) = z;
    }
  }
  __syncthreads();

  mfma_conv<64, 32, 7, 6, 0, WB_C1, PACKED>(wp, cw1, cb1, RB, RA, tid);  __syncthreads();
  mfma_conv<32, 64, 6, 7, 0, WB_C2, PACKED>(wp, cw2, cb2, RA, RB, tid);  __syncthreads();
  mfma_conv<64, 128, 7, 8, 0, WB_C3, PACKED>(wp, cw3, cb3, RB, RA, tid); __syncthreads();
  mfma_conv<128, 64, 8, 7, 2, WB_C4, PACKED>(wp, cw4, cb4, RA, RB, tid); __syncthreads();  // flat [bl][576]
  mfma_fc<64, 128, 7, 8, 0, 1, WB_F1, PACKED>(wp, fw1, fb1, RB, RA, tid); __syncthreads(); // flat [R][128]
  mfma_fc<128, 64, 8, 7, 0, 1, WB_F2, PACKED>(wp, fw2, fb2, RA, RB, tid); __syncthreads();// flat [R][64]
  mfma_fc<64, 32, 7, 6, 1, 0, WB_F3, PACKED>(wp, fw3, fb3, RB, RA, tid);  __syncthreads();// rs [bl][11][32]

  char* rs = RA;                 // 11264 B, live until the end
  char* a1 = RB;                 // [bl][11][16] 5632 B
  char* a2 = RA + 11264;         // [bl][11][8]  2816 B
  char* a3 = RB + 5632;          // [bl][11][4]  1408 B
  char* a4 = RA + 14080;         // [bl][11][2]   704 B
  char* a5 = RB + 7040;          // [bl][11][1]   352 B

  mfma_conv<32, 16, 6, 5, 0, WB_A1, PACKED>(wp, aw1, ab1, rs, a1, tid);  __syncthreads();
  valu_conv<16, 8, 5, -1>(aw2, ab2, a1, a2, tid);     __syncthreads();
  valu_conv<8, 4, -1, -1>(aw3, ab3, a2, a3, tid);     __syncthreads();
  valu_conv<4, 2, -1, -1>(aw4, ab4, a3, a4, tid);     __syncthreads();
  valu_conv<2, 1, -1, -1>(aw5, ab5, a4, a5, tid);     __syncthreads();

  // logits[b][o] = lb[o] + sum_t a5[b][t] * lw[o][t]
  if (p < 9){
    float acc = lb[p];
    #pragma unroll
    for (int t = 0; t < 9; ++t)
      acc = fmaf(lw[p*9 + t], bf2f(*(const unsigned short*)(a5 + (bl*11 + t + 1)*2)), acc);
    logits_s[bl*9 + p] = acc;
  }
  __syncthreads();

  if (p == 0){
    float m = -1e30f;
    #pragma unroll
    for (int t = 0; t < 9; ++t) m = fmaxf(m, logits_s[bl*9 + t]);
    float s = 0.f, ex[9];
    #pragma unroll
    for (int t = 0; t < 9; ++t){ ex[t] = __expf(logits_s[bl*9 + t] - m); s += ex[t]; }
    float inv = 1.f / s;
    #pragma unroll
    for (int t = 0; t < 9; ++t) att_s[bl*9 + t] = ex[t]*inv;
  }
  __syncthreads();

  // sub[b][s] = sum_t rs[b][s][t] * att[b][t]   (rs: [bl][11][32] swz<6>)
  {
    int s = p;
    float acc = 0.f;
    #pragma unroll
    for (int t = 0; t < 9; ++t){
      unsigned byte = (unsigned)(((bl*11 + t + 1)*32 + s)*2);
      acc = fmaf(bf2f(*(const unsigned short*)(rs + swz<6>(byte))), att_s[bl*9 + t], acc);
    }
    sub_s[bl*32 + s] = acc;
  }
  __syncthreads();

  // out[b][e] = 10 * sum_s mapping[id[b]][e][s] * sub[b][s]
  {
    const int b = b0 + bl;
    const size_t id = (size_t)ident[b];
    const float* mb = mapping + id*53*32;
    float subv[32];
    #pragma unroll
    for (int s = 0; s < 32; ++s) subv[s] = sub_s[bl*32 + s];
    for (int e = p; e < 53; e += 32){
      const float4* mrow4 = (const float4*)(mb + e*32);
      float acc = 0.f;
      #pragma unroll
      for (int s4 = 0; s4 < 8; ++s4){
        float4 mv = mrow4[s4];
        acc = fmaf(mv.x, subv[s4*4+0], acc);
        acc = fmaf(mv.y, subv[s4*4+1], acc);
        acc = fmaf(mv.z, subv[s4*4+2], acc);
        acc = fmaf(mv.w, subv[s4*4+3], acc);
      }
      out[(size_t)b*53 + e] = 10.f*acc;
    }
  }
}

extern "C" void kernel_launch(void* const* d_in, const int* in_sizes, int n_in,
                              void* d_out, int out_size, void* d_ws, size_t ws_size,
                              hipStream_t stream) {
  const float* x    = (const float*)d_in[0];
  const int*   ident= (const int*)  d_in[1];
  const float* cw1  = (const float*)d_in[2];  const float* cb1 = (const float*)d_in[3];
  const float* cw2  = (const float*)d_in[4];  const float* cb2 = (const float*)d_in[5];
  const float* cw3  = (const float*)d_in[6];  const float* cb3 = (const float*)d_in[7];
  const float* cw4  = (const float*)d_in[8];  const float* cb4 = (const float*)d_in[9];
  const float* fw1  = (const float*)d_in[10]; const float* fb1 = (const float*)d_in[11];
  const float* fw2  = (const float*)d_in[12]; const float* fb2 = (const float*)d_in[13];
  const float* fw3  = (const float*)d_in[14]; const float* fb3 = (const float*)d_in[15];
  const float* aw1  = (const float*)d_in[16]; const float* ab1 = (const float*)d_in[17];
  const float* aw2  = (const float*)d_in[18]; const float* ab2 = (const float*)d_in[19];
  const float* aw3  = (const float*)d_in[20]; const float* ab3 = (const float*)d_in[21];
  const float* aw4  = (const float*)d_in[22]; const float* ab4 = (const float*)d_in[23];
  const float* aw5  = (const float*)d_in[24]; const float* ab5 = (const float*)d_in[25];
  const float* lw   = (const float*)d_in[26]; const float* lb  = (const float*)d_in[27];
  const float* mapping = (const float*)d_in[28];

  const int B = 32768;
  dim3 grid(B / NB), block(THREADS);

  const bool packed = ws_size >= (size_t)(WP_TOTAL * 2);
  short* wpk = (short*)d_ws;

  if (packed){
    pack_weights<<<dim3((WP_TOTAL + 255)/256), dim3(256), 0, stream>>>(
        cw1, cw2, cw3, cw4, fw1, fw2, fw3, aw1, wpk);
    fused_expr_kernel<true><<<grid, block, 0, stream>>>(
        x, ident, cw1, cb1, cw2, cb2, cw3, cb3, cw4, cb4,
        fw1, fb1, fw2, fb2, fw3, fb3,
        aw1, ab1, aw2, ab2, aw3, ab3, aw4, ab4, aw5, ab5,
        lw, lb, mapping, wpk, (float*)d_out);
  } else {
    fused_expr_kernel<false><<<grid, block, 0, stream>>>(
        x, ident, cw1, cb1, cw2, cb2, cw3, cb3, cw4, cb4,
        fw1, fb1, fw2, fb2, fw3, fb3,
        aw1, ab1, aw2, ab2, aw3, ab3, aw4, ab4, aw5, ab5,
        lw, lb, mapping, wpk, (float*)d_out);
  }
}

// Round 4
// 142.240 us; speedup vs baseline: 7.0712x; 1.1684x over previous
//
#include <hip/hip_runtime.h>
#include <hip/hip_bf16.h>
#include <math.h>

#define THREADS 512
#define WAVES 8
#define NB 16            // batches per block -> M = 144 rows, 9 M-tiles

typedef __attribute__((ext_vector_type(8))) short bf16x8;
typedef __attribute__((ext_vector_type(4))) float f32x4;

__device__ __forceinline__ float leaky(float x){ return x >= 0.f ? x : 0.02f*x; }
__device__ __forceinline__ float fast_tanh(float x){
  float e = __expf(2.f*x);
  return 1.f - 2.f/(e + 1.f);
}

__device__ __forceinline__ unsigned short f2bf(float f){
  union { float f; unsigned u; } v; v.f = f;
  unsigned r = (v.u + 0x7FFFu + ((v.u >> 16) & 1u)) >> 16;
  return (unsigned short)r;
}
__device__ __forceinline__ float bf2f(unsigned short h){
  union { unsigned u; float f; } v; v.u = ((unsigned)h) << 16;
  return v.f;
}
__device__ __forceinline__ unsigned pack2bf(float a, float b){
  float2 t; t.x = a; t.y = b;
  __hip_bfloat162 h = __float22bfloat162_rn(t);
  union { __hip_bfloat162 h; unsigned u; } c; c.h = h;
  return c.u;
}

template<int L2R>
__device__ __forceinline__ unsigned swz(unsigned b){
  if constexpr (L2R < 0) return b;
  else return b ^ (((b >> L2R) & 7u) << 4);
}

__device__ __forceinline__ f32x4 mfma16(bf16x8 a, bf16x8 b, f32x4 c){
  return __builtin_amdgcn_mfma_f32_16x16x32_bf16(a, b, c, 0, 0, 0);
}

// ---- packed weight layout offsets (bf16 elements), 512 per fragment ----
#define WB_C1 0
#define WB_C2 6144
#define WB_C3 12288
#define WB_C4 36864
#define WB_F1 61440
#define WB_F2 69632
#define WB_F3 77824
#define WB_A1 79872
#define WB_A2 81408
#define WB_A3 82432
#define WB_A4 82944
#define WB_A5 83456
#define WP_TOTAL 83968   // elements; *2 = 167936 bytes

__global__ void pack_weights(
    const float* __restrict__ cw1, const float* __restrict__ cw2,
    const float* __restrict__ cw3, const float* __restrict__ cw4,
    const float* __restrict__ fw1, const float* __restrict__ fw2,
    const float* __restrict__ fw3, const float* __restrict__ aw1,
    const float* __restrict__ aw2, const float* __restrict__ aw3,
    const float* __restrict__ aw4, const float* __restrict__ aw5,
    short* __restrict__ wp)
{
  int g = blockIdx.x*256 + threadIdx.x;
  if (g >= WP_TOTAL) return;
  const float* w; int base, l2cp, cinw, cout, KS; bool conv;
  if      (g < WB_C2){ w=cw1; base=WB_C1; l2cp=6; cinw=64;  cout=32;  KS=6;  conv=true; }
  else if (g < WB_C3){ w=cw2; base=WB_C2; l2cp=5; cinw=32;  cout=64;  KS=3;  conv=true; }
  else if (g < WB_C4){ w=cw3; base=WB_C3; l2cp=6; cinw=64;  cout=128; KS=6;  conv=true; }
  else if (g < WB_F1){ w=cw4; base=WB_C4; l2cp=7; cinw=128; cout=64;  KS=12; conv=true; }
  else if (g < WB_F2){ w=fw1; base=WB_F1; l2cp=6; cinw=64;  cout=128; KS=2;  conv=false; }
  else if (g < WB_F3){ w=fw2; base=WB_F2; l2cp=7; cinw=128; cout=64;  KS=4;  conv=false; }
  else if (g < WB_A1){ w=fw3; base=WB_F3; l2cp=6; cinw=64;  cout=32;  KS=2;  conv=false; }
  else if (g < WB_A2){ w=aw1; base=WB_A1; l2cp=5; cinw=32;  cout=16;  KS=3;  conv=true; }
  else if (g < WB_A3){ w=aw2; base=WB_A2; l2cp=4; cinw=16;  cout=8;   KS=2;  conv=true; }
  else if (g < WB_A4){ w=aw3; base=WB_A3; l2cp=3; cinw=8;   cout=4;   KS=1;  conv=true; }
  else if (g < WB_A5){ w=aw4; base=WB_A4; l2cp=3; cinw=4;   cout=2;   KS=1;  conv=true; }
  else               { w=aw5; base=WB_A5; l2cp=3; cinw=2;   cout=1;   KS=1;  conv=true; }
  int local = g - base;
  int frag = local >> 9;
  int lane = (local >> 3) & 63;
  int j    = local & 7;
  int nt = frag / KS, ks = frag - nt*KS;
  int hi = lane >> 4, lo = lane & 15;
  int k = ks*32 + hi*8 + j;
  int n = nt*16 + lo;
  float v = 0.f;
  if (n < cout){
    if (conv){
      int dt = k >> l2cp, ci = k & ((1<<l2cp)-1);
      if (dt < 3 && ci < cinw) v = w[((size_t)n*cinw + ci)*3 + dt];
    } else {
      v = w[(size_t)n*cinw + k];
    }
  }
  wp[g] = (short)f2bf(v);
}

// ---------------- unified MFMA layer (operand-swapped: D[n][R]) ----------------
// IN_CONV: input padded conv layout [bl][11][CINP], A element index = ridx*CINP + k
// else (fc): flat [R][K=CINP]
// OUT_MODE: 0 conv-padded [bl][11][STORE_CH] (+pad-zero rows), 1 flat [R][COUT],
//           2 conv4-flat [bl][576] (c*9+t), 3 conv-layout no-pad-loop
// ACT: 0 leaky, 1 tanh
template<int CINP, int CINW, int COUT, int STORE_CH, int KS, int L2RI, int L2RO,
         bool IN_CONV, int OUT_MODE, int ACT, int LBASE, bool PACKED>
__device__ __forceinline__ void mfma_layer(
    const short* __restrict__ wp, const float* __restrict__ w,
    const float* __restrict__ bias, const char* __restrict__ inb,
    char* __restrict__ outb, int tid)
{
  constexpr int NT = (COUT + 15)/16;
  constexpr int L2CINP = (CINP==8?3:CINP==16?4:CINP==32?5:CINP==64?6:7);
  const int wave = tid >> 6, lane = tid & 63;
  const int hi = lane >> 4, lo = lane & 15;

  int nt0, mlo, mhi;
  if constexpr (NT >= WAVES){ nt0 = wave; mlo = 0; mhi = 9; }
  else { constexpr int WPN = WAVES/NT; int seg = wave / NT; nt0 = wave - seg*NT;
         mlo = (9*seg)/WPN; mhi = (9*(seg+1))/WPN; }

  // B operand = weights (A-role in swapped mfma): lane -> (n = lo, k = hi*8+j)
  bf16x8 Bf[KS];
  #pragma unroll
  for (int ks = 0; ks < KS; ++ks){
    if constexpr (PACKED){
      Bf[ks] = *(const bf16x8*)(wp + LBASE + ((nt0*KS + ks) << 9) + lane*8);
    } else {
      int n = nt0*16 + lo;
      #pragma unroll
      for (int j = 0; j < 8; ++j){
        int k = ks*32 + hi*8 + j;
        float v = 0.f;
        if (n < COUT){
          if constexpr (IN_CONV){
            int dt = k >> L2CINP, ci = k & (CINP-1);
            if (dt < 3 && ci < CINW) v = w[((size_t)n*CINW + ci)*3 + dt];
          } else {
            v = w[(size_t)n*CINP + k];
          }
        }
        Bf[ks][j] = (short)f2bf(v);
      }
    }
  }

  // bias: 4 consecutive channels per lane in swapped C-layout
  float bb[4];
  #pragma unroll
  for (int r = 0; r < 4; ++r){
    int n = nt0*16 + hi*4 + r;
    bb[r] = (n < COUT) ? bias[n] : 0.f;
  }

  const unsigned hi16 = (unsigned)hi * 16u;
  const int n0 = nt0*16 + hi*4;

  for (int m = mlo; m < mhi; ++m){
    int R = m*16 + lo;
    int bl2 = 0, t2 = 0, ridx = R;
    if constexpr (IN_CONV || OUT_MODE != 1){
      bl2 = R/9; t2 = R - bl2*9; ridx = bl2*11 + t2;
    }
    unsigned base_in;
    if constexpr (IN_CONV) base_in = ((unsigned)ridx << (L2CINP+1));
    else                   base_in = ((unsigned)R    << (L2CINP+1));

    f32x4 acc = (f32x4){bb[0], bb[1], bb[2], bb[3]};
    #pragma unroll
    for (int ks = 0; ks < KS; ++ks){
      unsigned byte0 = base_in + (unsigned)(ks*64) + hi16;
      bf16x8 Af = *(const bf16x8*)(inb + swz<L2RI>(byte0));
      acc = mfma16(Bf[ks], Af, acc);     // SWAPPED: D[n][R]
    }

    if constexpr (OUT_MODE == 2){
      #pragma unroll
      for (int r = 0; r < 4; ++r){
        int n = n0 + r;
        float vr = (ACT==0) ? leaky(acc[r]) : fast_tanh(acc[r]);
        unsigned byte = (unsigned)((bl2*576 + n*9 + t2)*2);
        *(short*)(outb + swz<L2RO>(byte)) = (short)f2bf(vr);
      }
    } else if constexpr (STORE_CH == 1){
      if (hi == 0){
        float vr = (ACT==0) ? leaky(acc[0]) : fast_tanh(acc[0]);
        *(short*)(outb + (unsigned)((ridx + 1)*2)) = (short)f2bf(vr);
      }
    } else {
      if (n0 < STORE_CH){
        float v[4];
        #pragma unroll
        for (int r = 0; r < 4; ++r){
          float vr = (ACT==0) ? leaky(acc[r]) : fast_tanh(acc[r]);
          if constexpr (STORE_CH > COUT){ if (n0 + r >= COUT) vr = 0.f; }
          v[r] = vr;
        }
        unsigned rowO = (OUT_MODE == 1) ? (unsigned)R : (unsigned)(ridx + 1);
        unsigned byte = rowO * (unsigned)(STORE_CH*2) + (unsigned)(n0*2);
        uint2 pk; pk.x = pack2bf(v[0], v[1]); pk.y = pack2bf(v[2], v[3]);
        *(uint2*)(outb + swz<L2RO>(byte)) = pk;
      }
    }
  }

  if constexpr (OUT_MODE == 0){
    // zero pad rows (t=0 and t=10) across all STORE_CH channels
    for (int i = tid; i < NB*2*STORE_CH/4; i += THREADS){
      int bl = i / (2*STORE_CH/4); int rem = i - bl*(2*STORE_CH/4);
      int side = rem / (STORE_CH/4); int c4 = rem - side*(STORE_CH/4);
      unsigned byte = (unsigned)(((bl*11 + side*10)*STORE_CH + c4*4)*2);
      uint2 z; z.x = 0u; z.y = 0u;
      *(uint2*)(outb + swz<L2RO>(byte)) = z;
    }
  }
}

// tail buffer offsets within RB
#define A2OFF 5760
#define A3OFF 8704
#define A4OFF 11648
#define A5OFF 14592

template<bool PACKED>
__global__ __launch_bounds__(THREADS, 4)
void fused_expr_kernel(
    const float* __restrict__ x, const int* __restrict__ ident,
    const float* __restrict__ cw1, const float* __restrict__ cb1,
    const float* __restrict__ cw2, const float* __restrict__ cb2,
    const float* __restrict__ cw3, const float* __restrict__ cb3,
    const float* __restrict__ cw4, const float* __restrict__ cb4,
    const float* __restrict__ fw1, const float* __restrict__ fb1,
    const float* __restrict__ fw2, const float* __restrict__ fb2,
    const float* __restrict__ fw3, const float* __restrict__ fb3,
    const float* __restrict__ aw1, const float* __restrict__ ab1,
    const float* __restrict__ aw2, const float* __restrict__ ab2,
    const float* __restrict__ aw3, const float* __restrict__ ab3,
    const float* __restrict__ aw4, const float* __restrict__ ab4,
    const float* __restrict__ aw5, const float* __restrict__ ab5,
    const float* __restrict__ lw,  const float* __restrict__ lb,
    const float* __restrict__ mapping, const short* __restrict__ wp,
    float* __restrict__ out)
{
  __shared__ __align__(16) char pool[67584];
  __shared__ float logits_s[NB*9];
  __shared__ float att_s[NB*9];
  __shared__ float sub_s[NB*32];

  char* RA = pool;            // 45056 bytes
  char* RB = pool + 45056;    // 22528 bytes

  const int tid = threadIdx.x;
  const int b0 = blockIdx.x * NB;
  const int p  = tid >> 4;    // 0..31
  const int bl = tid & 15;

  // ---- stage x (fp32, (B,9,64)) -> RB bf16 [bl][11][64] padded, swz<7>
  {
    const float4* xb4 = (const float4*)(x + (size_t)b0 * 576);
    for (int i = tid; i < NB*144; i += THREADS){
      int b = i / 144; int rem = i - b*144;     // rem = t*16 + c4
      int t = rem >> 4; int c4 = rem & 15;
      float4 v = xb4[i];
      uint2 pk;
      pk.x = pack2bf(v.x, v.y);
      pk.y = pack2bf(v.z, v.w);
      unsigned byte = (unsigned)(((b*11 + t + 1)*64 + c4*4)*2);
      *(uint2*)(RB + swz<7>(byte)) = pk;
    }
    for (int i = tid; i < 512; i += THREADS){
      int b = i >> 5; int rem = i & 31;
      int side = rem >> 4; int c4 = rem & 15;
      unsigned byte = (unsigned)(((b*11 + side*10)*64 + c4*4)*2);
      uint2 z; z.x = 0u; z.y = 0u;
      *(uint2*)(RB + swz<7>(byte)) = z;
    }
  }
  __syncthreads();

  //               CINP CINW COUT SC  KS  LI LO  CONV OM ACT
  mfma_layer<64, 64, 32, 32, 6, 7, 6, true, 0, 0, WB_C1, PACKED>(wp, cw1, cb1, RB, RA, tid); __syncthreads();
  mfma_layer<32, 32, 64, 64, 3, 6, 7, true, 0, 0, WB_C2, PACKED>(wp, cw2, cb2, RA, RB, tid); __syncthreads();
  mfma_layer<64, 64,128,128, 6, 7, 8, true, 0, 0, WB_C3, PACKED>(wp, cw3, cb3, RB, RA, tid); __syncthreads();
  mfma_layer<128,128,64, 64,12, 8, 7, true, 2, 0, WB_C4, PACKED>(wp, cw4, cb4, RA, RB, tid); __syncthreads(); // flat [bl][576]
  mfma_layer<64, 64,128,128, 2, 7, 8, false,1, 0, WB_F1, PACKED>(wp, fw1, fb1, RB, RA, tid); __syncthreads(); // flat [R][128]
  mfma_layer<128,128,64, 64, 4, 8, 7, false,1, 0, WB_F2, PACKED>(wp, fw2, fb2, RA, RB, tid); __syncthreads(); // flat [R][64]
  mfma_layer<64, 64, 32, 32, 2, 7, 6, false,0, 1, WB_F3, PACKED>(wp, fw3, fb3, RB, RA, tid); __syncthreads(); // rs [bl][11][32]

  char* rs = RA;               // [bl][11][32] swz6, live until the end
  char* a1 = RB;               // [bl][11][16] swz5, 5632 B
  char* a2 = RB + A2OFF;       // [bl][11][8]  2816 B (no swz)
  char* a3 = RB + A3OFF;       // [bl][11][8]  (4 real ch + zero pad)
  char* a4 = RB + A4OFF;       // [bl][11][8]  (2 real ch + zero pad)
  char* a5 = RB + A5OFF;       // [bl][11][1]  352 B

  mfma_layer<32, 32, 16, 16, 3, 6, 5, true, 0, 0, WB_A1, PACKED>(wp, aw1, ab1, rs, a1, tid); __syncthreads();
  mfma_layer<16, 16,  8,  8, 2, 5,-1, true, 0, 0, WB_A2, PACKED>(wp, aw2, ab2, a1, a2, tid); __syncthreads();
  mfma_layer< 8,  8,  4,  8, 1,-1,-1, true, 0, 0, WB_A3, PACKED>(wp, aw3, ab3, a2, a3, tid); __syncthreads();
  mfma_layer< 8,  4,  2,  8, 1,-1,-1, true, 0, 0, WB_A4, PACKED>(wp, aw4, ab4, a3, a4, tid); __syncthreads();
  mfma_layer< 8,  2,  1,  1, 1,-1,-1, true, 3, 0, WB_A5, PACKED>(wp, aw5, ab5, a4, a5, tid); __syncthreads();

  // logits[b][o] = lb[o] + sum_t a5[b][t] * lw[o][t]
  if (p < 9){
    float acc = lb[p];
    #pragma unroll
    for (int t = 0; t < 9; ++t)
      acc = fmaf(lw[p*9 + t], bf2f(*(const unsigned short*)(a5 + (bl*11 + t + 1)*2)), acc);
    logits_s[bl*9 + p] = acc;
  }
  __syncthreads();

  if (p == 0){
    float m = -1e30f;
    #pragma unroll
    for (int t = 0; t < 9; ++t) m = fmaxf(m, logits_s[bl*9 + t]);
    float s = 0.f, ex[9];
    #pragma unroll
    for (int t = 0; t < 9; ++t){ ex[t] = __expf(logits_s[bl*9 + t] - m); s += ex[t]; }
    float inv = 1.f / s;
    #pragma unroll
    for (int t = 0; t < 9; ++t) att_s[bl*9 + t] = ex[t]*inv;
  }
  __syncthreads();

  // sub[b][s] = sum_t rs[b][s][t] * att[b][t]
  {
    int s = p;
    float acc = 0.f;
    #pragma unroll
    for (int t = 0; t < 9; ++t){
      unsigned byte = (unsigned)(((bl*11 + t + 1)*32 + s)*2);
      acc = fmaf(bf2f(*(const unsigned short*)(rs + swz<6>(byte))), att_s[bl*9 + t], acc);
    }
    sub_s[bl*32 + s] = acc;
  }
  __syncthreads();

  // out[b][e] = 10 * sum_s mapping[id[b]][e][s] * sub[b][s]
  {
    const int b = b0 + bl;
    const size_t id = (size_t)ident[b];
    const float* mb = mapping + id*53*32;
    float subv[32];
    #pragma unroll
    for (int s = 0; s < 32; ++s) subv[s] = sub_s[bl*32 + s];
    for (int e = p; e < 53; e += 32){
      const float4* mrow4 = (const float4*)(mb + e*32);
      float acc = 0.f;
      #pragma unroll
      for (int s4 = 0; s4 < 8; ++s4){
        float4 mv = mrow4[s4];
        acc = fmaf(mv.x, subv[s4*4+0], acc);
        acc = fmaf(mv.y, subv[s4*4+1], acc);
        acc = fmaf(mv.z, subv[s4*4+2], acc);
        acc = fmaf(mv.w, subv[s4*4+3], acc);
      }
      out[(size_t)b*53 + e] = 10.f*acc;
    }
  }
}

extern "C" void kernel_launch(void* const* d_in, const int* in_sizes, int n_in,
                              void* d_out, int out_size, void* d_ws, size_t ws_size,
                              hipStream_t stream) {
  const float* x    = (const float*)d_in[0];
  const int*   ident= (const int*)  d_in[1];
  const float* cw1  = (const float*)d_in[2];  const float* cb1 = (const float*)d_in[3];
  const float* cw2  = (const float*)d_in[4];  const float* cb2 = (const float*)d_in[5];
  const float* cw3  = (const float*)d_in[6];  const float* cb3 = (const float*)d_in[7];
  const float* cw4  = (const float*)d_in[8];  const float* cb4 = (const float*)d_in[9];
  const float* fw1  = (const float*)d_in[10]; const float* fb1 = (const float*)d_in[11];
  const float* fw2  = (const float*)d_in[12]; const float* fb2 = (const float*)d_in[13];
  const float* fw3  = (const float*)d_in[14]; const float* fb3 = (const float*)d_in[15];
  const float* aw1  = (const float*)d_in[16]; const float* ab1 = (const float*)d_in[17];
  const float* aw2  = (const float*)d_in[18]; const float* ab2 = (const float*)d_in[19];
  const float* aw3  = (const float*)d_in[20]; const float* ab3 = (const float*)d_in[21];
  const float* aw4  = (const float*)d_in[22]; const float* ab4 = (const float*)d_in[23];
  const float* aw5  = (const float*)d_in[24]; const float* ab5 = (const float*)d_in[25];
  const float* lw   = (const float*)d_in[26]; const float* lb  = (const float*)d_in[27];
  const float* mapping = (const float*)d_in[28];

  const int B = 32768;
  dim3 grid(B / NB), block(THREADS);

  const bool packed = ws_size >= (size_t)(WP_TOTAL * 2);
  short* wpk = (short*)d_ws;

  if (packed){
    pack_weights<<<dim3(WP_TOTAL/256), dim3(256), 0, stream>>>(
        cw1, cw2, cw3, cw4, fw1, fw2, fw3, aw1, aw2, aw3, aw4, aw5, wpk);
    fused_expr_kernel<true><<<grid, block, 0, stream>>>(
        x, ident, cw1, cb1, cw2, cb2, cw3, cb3, cw4, cb4,
        fw1, fb1, fw2, fb2, fw3, fb3,
        aw1, ab1, aw2, ab2, aw3, ab3, aw4, ab4, aw5, ab5,
        lw, lb, mapping, wpk, (float*)d_out);
  } else {
    fused_expr_kernel<false><<<grid, block, 0, stream>>>(
        x, ident, cw1, cb1, cw2, cb2, cw3, cb3, cw4, cb4,
        fw1, fb1, fw2, fb2, fw3, fb3,
        aw1, ab1, aw2, ab2, aw3, ab3, aw4, ab4, aw5, ab5,
        lw, lb, mapping, wpk, (float*)d_out);
  }
}